// Round 3
// baseline (3646.938 us; speedup 1.0000x reference)
//
#include <hip/hip_runtime.h>
#include <hip/hip_bf16.h>

#define N_NODES 20000
#define R_REL   48
#define NBASES  12
#define E_EDGES 640000
#define EPB     16

// ---------- dual-dtype scalar access (flag: 1 = fp32, 0 = bf16) -------------
__device__ inline float loadF(const void* p, long long idx, int isf32) {
    if (isf32 != 0) return ((const float*)p)[idx];
    return __bfloat162float(((const __hip_bfloat16*)p)[idx]);
}

__device__ inline void storeF(void* p, long long idx, int isf32, float v) {
    if (isf32 != 0) ((float*)p)[idx] = v;
    else ((__hip_bfloat16*)p)[idx] = __float2bfloat16(v);
}

// ---------- dtype probe ------------------------------------------------------
__global__ void detect_dtype(const void* emb, int* flag) {
    if (threadIdx.x == 0 && blockIdx.x == 0) {
        const unsigned short* h = (const unsigned short*)emb;
        int f32 = 0;
        for (int k = 0; k < 256; k++) {
            unsigned int bits = ((unsigned int)h[k]) << 16;
            float v = __uint_as_float(bits);
            if (!(fabsf(v) < 1000.0f)) f32 = 1;   // huge/NaN -> fp32 data
        }
        *flag = f32;
    }
}

// ---------- zero helpers -----------------------------------------------------
__global__ void zero_f32(float* p, int n) {
    int i = blockIdx.x * 256 + threadIdx.x;
    if (i < n) p[i] = 0.0f;
}

__global__ void zero_i32(int* p, int n) {
    int i = blockIdx.x * 256 + threadIdx.x;
    if (i < n) p[i] = 0;
}

// ---------- edge prep --------------------------------------------------------
__global__ void count_kernel(const int* dst, const int* typ,
                             float* cnt, int* hist) {
    int e = blockIdx.x * 256 + threadIdx.x;
    if (e < E_EDGES) {
        int t = typ[e];
        atomicAdd(&cnt[t * N_NODES + dst[e]], 1.0f);
        atomicAdd(&hist[t], 1);
    }
}

__global__ void inv_kernel(float* p) {
    int i = blockIdx.x * 256 + threadIdx.x;   // < R*N exactly
    float c = p[i];
    p[i] = (c > 0.0f) ? (1.0f / c) : 0.0f;
}

__global__ void prefix_kernel(const int* hist, int* bins, int* cursor) {
    if (threadIdx.x == 0 && blockIdx.x == 0) {
        int acc = 0;
        for (int r = 0; r < R_REL; r++) {
            bins[r] = acc;
            cursor[r] = acc;
            acc += hist[r];
        }
        bins[R_REL] = acc;
    }
}

__global__ void scatter_kernel(const int* src, const int* dst, const int* typ,
                               int* cursor, int* s_src, int* s_dst) {
    int e = blockIdx.x * 256 + threadIdx.x;
    if (e < E_EDGES) {
        int t = typ[e];
        int p = atomicAdd(&cursor[t], 1);
        s_src[p] = src[e];
        s_dst[p] = dst[e];
    }
}

// ---------- W build: W[r][i][o] = sum_b comp[r][b]*basis[b][i][o] -----------
__global__ void build_w(const void* comp, const void* basis,
                        __hip_bfloat16* W, const int* flagp) {
    int r = blockIdx.x;
    int idx = blockIdx.y * 256 + threadIdx.x;   // 0..16383 = i*128+o
    int isf32 = *flagp;
    float acc = 0.0f;
    for (int b = 0; b < NBASES; b++) {
        acc += loadF(comp, r * NBASES + b, isf32) *
               loadF(basis, b * 16384 + idx, isf32);
    }
    W[((long long)r << 14) + idx] = __float2bfloat16(acc);
}

// ---------- root: outf[n][o] = bias[o] + sum_i x[n][i]*root[i][o] -----------
__global__ __launch_bounds__(128) void root_valu(
        const void* x, int xbase, int xld,
        const void* root, const void* bias,
        float* outf, const int* flagp) {
    __shared__ float xs[128];
    int n = blockIdx.x;
    int o = threadIdx.x;
    int isf32 = *flagp;
    xs[o] = loadF(x, (long long)xbase + (long long)n * xld + o, isf32);
    __syncthreads();
    float acc = loadF(bias, o, isf32);
    for (int i = 0; i < 128; i++)
        acc += xs[i] * loadF(root, i * 128 + o, isf32);
    outf[(long long)n * 128 + o] = acc;
}

// ---------- edge: outf[dst] += inv * (x[src] @ W_r) -------------------------
__global__ __launch_bounds__(256) void edge_valu(
        const int* s_src, const int* s_dst, const int* bins, const float* inv,
        const void* x, int xbase, int xld,
        const __hip_bfloat16* W, float* outf, const int* flagp) {
    __shared__ float xs[EPB][128];
    __shared__ float lscl[EPB];
    __shared__ int   ldst[EPB];
    int r = blockIdx.x;
    int rs = bins[r];
    int re = bins[r + 1];
    int e0 = rs + blockIdx.y * EPB;
    if (e0 >= re) return;
    int isf32 = *flagp;
    int tid = threadIdx.x;

    if (tid < EPB) {
        int e = e0 + tid;
        if (e < re) {
            int d = s_dst[e];
            ldst[tid] = d;
            lscl[tid] = inv[(long long)r * N_NODES + d];
        } else {
            ldst[tid] = 0;
            lscl[tid] = 0.0f;   // marks invalid tail edge
        }
    }
    for (int s = tid; s < EPB * 128; s += 256) {
        int er = s >> 7;
        int c = s & 127;
        int e = e0 + er;
        int ec = (e < re) ? e : (re - 1);
        int srow = s_src[ec];
        xs[er][c] = loadF(x, (long long)xbase + (long long)srow * xld + c, isf32);
    }
    __syncthreads();

    int col = tid & 127;
    int g = tid >> 7;                   // 0/1 -> edges g*8 .. g*8+7
    const __hip_bfloat16* Wr = W + ((long long)r << 14);
    float acc[8];
    for (int j = 0; j < 8; j++) acc[j] = 0.0f;
    for (int i = 0; i < 128; i++) {
        float w = __bfloat162float(Wr[i * 128 + col]);
#pragma unroll
        for (int j = 0; j < 8; j++)
            acc[j] += w * xs[g * 8 + j][i];
    }
    for (int j = 0; j < 8; j++) {
        int e = g * 8 + j;
        float s = lscl[e];
        if (s != 0.0f)
            atomicAdd(&outf[(long long)ldst[e] * 128 + col], acc[j] * s);
    }
}

// ---------- epilogues --------------------------------------------------------
__global__ void relu_store(const float* outf, void* out, int slot,
                           const int* flagp) {
    int idx = blockIdx.x * 256 + threadIdx.x;   // < N*128 exactly
    int n = idx >> 7;
    int c = idx & 127;
    float v = fmaxf(outf[idx], 0.0f);
    storeF(out, (long long)n * 512 + slot + c, *flagp, v);
}

__global__ void copy_emb(const void* emb, void* out, const int* flagp) {
    int idx = blockIdx.x * 256 + threadIdx.x;   // < N*128 exactly
    int n = idx >> 7;
    int c = idx & 127;
    int isf32 = *flagp;
    float v = loadF(emb, idx, isf32);
    storeF(out, (long long)n * 512 + 384 + c, isf32, v);
}

// ---------- launch -----------------------------------------------------------
extern "C" void kernel_launch(void* const* d_in, const int* in_sizes, int n_in,
                              void* d_out, int out_size, void* d_ws, size_t ws_size,
                              hipStream_t stream) {
    const void* emb  = d_in[0];
    const int* esrc = (const int*)d_in[1];
    const int* edst = (const int*)d_in[2];
    const int* etyp = (const int*)d_in[3];
    const void* comp[3];
    const void* basis[3];
    const void* root[3];
    const void* bias[3];
    for (int l = 0; l < 3; l++) {
        comp[l]  = d_in[4 + l * 4];
        basis[l] = d_in[5 + l * 4];
        root[l]  = d_in[6 + l * 4];
        bias[l]  = d_in[7 + l * 4];
    }

    char* ws = (char*)d_ws;
    int*   flag   = (int*)(ws + 0);                           // 256 B
    float* inv    = (float*)(ws + 256);                       // 3,840,000 B
    int*   s_src  = (int*)(ws + 3840256);                     // 2,560,000 B
    int*   s_dst  = (int*)(ws + 6400256);                     // 2,560,000 B
    int*   ctrl   = (int*)(ws + 8960256);                     // 1,024 B
    int*   hist   = ctrl + 0;                                 // 48
    int*   cursor = ctrl + 64;                                // 48
    int*   bins   = ctrl + 128;                               // 49
    __hip_bfloat16* W = (__hip_bfloat16*)(ws + 8961280);      // 1,572,864 B
    float* outf   = (float*)(ws + 10534144);                  // 10,240,000 B

    detect_dtype<<<1, 64, 0, stream>>>(emb, flag);
    zero_f32<<<3750, 256, 0, stream>>>(inv, R_REL * N_NODES);
    zero_i32<<<1, 256, 0, stream>>>(ctrl, 256);

    count_kernel<<<2500, 256, 0, stream>>>(edst, etyp, inv, hist);
    inv_kernel<<<3750, 256, 0, stream>>>(inv);
    prefix_kernel<<<1, 64, 0, stream>>>(hist, bins, cursor);
    scatter_kernel<<<2500, 256, 0, stream>>>(esrc, edst, etyp, cursor,
                                             s_src, s_dst);
    copy_emb<<<10000, 256, 0, stream>>>(emb, d_out, flag);

    const void* xin = emb;
    int xbase = 0;
    int xld = 128;
    const int slots[3] = {256, 128, 0};   // x1, x2, x3 column offsets
    for (int l = 0; l < 3; l++) {
        build_w<<<dim3(48, 64), 256, 0, stream>>>(comp[l], basis[l], W, flag);
        root_valu<<<20000, 128, 0, stream>>>(xin, xbase, xld, root[l], bias[l],
                                             outf, flag);
        edge_valu<<<dim3(48, 1000), 256, 0, stream>>>(s_src, s_dst, bins, inv,
                                                      xin, xbase, xld,
                                                      W, outf, flag);
        relu_store<<<10000, 256, 0, stream>>>(outf, d_out, slots[l], flag);
        xin = d_out;
        xbase = slots[l];
        xld = 512;
    }
    (void)in_sizes; (void)n_in; (void)out_size; (void)ws_size;
}